// Round 12
// baseline (6930.797 us; speedup 1.0000x reference)
//
#include <hip/hip_runtime.h>
#include <cmath>

#define LOG2E 1.44269504088896340736f
#define TMAX 2048

#if __has_builtin(__builtin_amdgcn_exp2f)
#define EXP2F(x) __builtin_amdgcn_exp2f(x)
#else
#define EXP2F(x) exp2f(x)
#endif
#if __has_builtin(__builtin_amdgcn_rcpf)
#define RCPF(x) __builtin_amdgcn_rcpf(x)
#else
#define RCPF(x) (1.0f / (x))
#endif

typedef float float2v __attribute__((ext_vector_type(2)));
typedef float float4v __attribute__((ext_vector_type(4)));

__device__ __forceinline__ float fexp(float x)  { return EXP2F(x * LOG2E); }
// tanh(x) = 1 - 2/(1 + e^{2x})
__device__ __forceinline__ float ftanh(float x) { return 1.0f - 2.0f * RCPF(1.0f + EXP2F(x * (2.0f * LOG2E))); }
// _step(x) = (tanh(5x)+1)/2 = sigmoid(10x)
__device__ __forceinline__ float fstep(float x) { return RCPF(1.0f + EXP2F(x * (-10.0f * LOG2E))); }
__device__ __forceinline__ float fsinh(float x) { float e = fexp(x); return 0.5f * (e - RCPF(e)); }

__device__ __forceinline__ int fadd_i(int a, int b) {
    return __builtin_bit_cast(int, __builtin_bit_cast(float, a) + __builtin_bit_cast(float, b));
}

// full-wave (64 lane) sum via DPP tree; TOTAL VALID IN LANE 63 ONLY.
__device__ __forceinline__ float wave_sum63(float x) {
    int v = __builtin_bit_cast(int, x);
    v = fadd_i(v, __builtin_amdgcn_update_dpp(0, v, 0x111, 0xF, 0xF, true)); // row_shr:1
    v = fadd_i(v, __builtin_amdgcn_update_dpp(0, v, 0x112, 0xF, 0xF, true)); // row_shr:2
    v = fadd_i(v, __builtin_amdgcn_update_dpp(0, v, 0x114, 0xF, 0xF, true)); // row_shr:4
    v = fadd_i(v, __builtin_amdgcn_update_dpp(0, v, 0x118, 0xF, 0xF, true)); // row_shr:8
    v = fadd_i(v, __builtin_amdgcn_update_dpp(0, v, 0x142, 0xA, 0xF, true)); // row_bcast:15
    v = fadd_i(v, __builtin_amdgcn_update_dpp(0, v, 0x143, 0xC, 0xF, true)); // row_bcast:31
    return __builtin_bit_cast(float, v);
}

// quad (4-lane) all-sum via 2 DPP quad_perm adds (valid in all 4 lanes)
__device__ __forceinline__ float quad_sum(float x) {
    int v = __builtin_bit_cast(int, x);
    v = fadd_i(v, __builtin_amdgcn_update_dpp(0, v, 0xB1, 0xF, 0xF, true)); // quad_perm [1,0,3,2]
    v = fadd_i(v, __builtin_amdgcn_update_dpp(0, v, 0x4E, 0xF, 0xF, true)); // quad_perm [2,3,0,1]
    return __builtin_bit_cast(float, v);
}

// broadcast lane l's value to all lanes (lands in SGPR)
__device__ __forceinline__ float rl(float x, int l) {
    return __builtin_bit_cast(float, __builtin_amdgcn_readlane(__builtin_bit_cast(int, x), l));
}

// packed fp32 fma: d = a*b + c on both 32-bit halves (one VOP3P inst)
__device__ __forceinline__ float2v pk_fma(float2v a, float2v b, float2v c) {
    float2v d;
    asm("v_pk_fma_f32 %0, %1, %2, %3" : "=v"(d) : "v"(a), "v"(b), "v"(c));
    return d;
}

__device__ __forceinline__ float2v vlo(float4v v) { return __builtin_shufflevector(v, v, 0, 1); }
__device__ __forceinline__ float2v vhi(float4v v) { return __builtin_shufflevector(v, v, 2, 3); }

// lgkmcnt-only barrier: ds_writes must be LDS-visible, but do NOT drain vmcnt
// (the per-step `out` global store would otherwise stall every wave here).
__device__ __forceinline__ void barrier_lgkm() {
    asm volatile("s_waitcnt lgkmcnt(0)" ::: "memory");
    __builtin_amdgcn_s_barrier();
    asm volatile("" ::: "memory");
}

__global__ __launch_bounds__(512, 1)
void exphydro_kernel(const float* __restrict__ g_snow, const float* __restrict__ g_water,
                     const float* __restrict__ g_pr, const float* __restrict__ g_tm,
                     const float* __restrict__ g_ld, const float* __restrict__ g_t,
                     const float* __restrict__ W1, const float* __restrict__ b1,
                     const float* __restrict__ W2, const float* __restrict__ b2,
                     const float* __restrict__ W3, const float* __restrict__ b3,
                     const float* __restrict__ W4, const float* __restrict__ b4,
                     float* __restrict__ out, int T, int B)
{
    const int tid  = threadIdx.x;
    const int lane = tid & 63;
    const int wid  = tid >> 6;      // 0..7; SIMD = wid&3 -> each SIMD hosts one
    const int samp = wid >> 2;      //   wave of sample 0 AND one of sample 1
    const int wq   = wid & 3;       // role within the sample's 4-wave team
    const int b0   = 2 * blockIdx.x;
    const int bs   = (b0 + samp < B) ? (b0 + samp) : (B - 1);
    const int qk   = lane & 3;      // L2: K-subslice (rows [qk*16, qk*16+16))
    const int qo   = lane >> 2;     // L2: output index within this team's slice
    const int col2 = 16 * wq + qo;  // L2 output column this lane computes

    // forcing series per sample (uniform grid: t dropped; dt read from g_t)
    __shared__ float s_pr[2][TMAX];
    __shared__ float s_tm[2][TMAX];
    __shared__ float s_ld[2][TMAX];
    // per-wave private h1 copy (in-wave DS order => no barrier)
    __shared__ __align__(16) float hc[8][64];
    // L3 partial exchange per sample, double-buffered across rhs calls
    __shared__ __align__(16) float partAB[2][2][4][64];

    {   // staging: half-block (256 threads) per sample, coalesced
        const int sh = tid >> 8;
        const int to = tid & 255;
        const int bb = (b0 + sh < B) ? (b0 + sh) : (B - 1);
        for (int j = to; j < T; j += 256) {
            s_pr[sh][j] = g_pr[bb * T + j];
            s_tm[sh][j] = g_tm[bb * T + j];
            s_ld[sh][j] = g_ld[bb * T + j];
        }
    }

    // uniform time grid (arange): dt constant; midpoint interp == average
    const float dtg  = g_t[1] - g_t[0];
    const float half = 0.5f * dtg;
    const float c6   = dtg * (1.0f / 6.0f);

    // --- weights (identical for both samples; indexed by role wq) ---
    float w1r[4];
#pragma unroll
    for (int j = 0; j < 4; ++j) w1r[j] = W1[j * 64 + lane];
    float b1v = b1[lane];
    // layer 2, N-split: lane computes output col2 over K-rows [qk*16, qk*16+16)
    float2v w2n[8];
#pragma unroll
    for (int k = 0; k < 8; ++k) {
        int r = qk * 16 + 2 * k;
        w2n[k] = float2v{W2[r * 64 + col2], W2[(r + 1) * 64 + col2]};
    }
    float b2s = b2[col2];
    // layer 3, K-split: team role wq owns rows [16*wq, 16*wq+16), lane = out col
    float w3f[16];
#pragma unroll
    for (int k = 0; k < 16; ++k) w3f[k] = W3[(16 * wq + k) * 64 + lane];
    float b3v = (wq == 0) ? b3[lane] : 0.0f;
    // layer 4: full, redundant per wave
    float w4r[5], b4r[5];
#pragma unroll
    for (int k = 0; k < 5; ++k) { w4r[k] = W4[lane * 5 + k]; b4r[k] = b4[k]; }

    __syncthreads();

    // full MLP from per-lane h1; o[0..4] VALID IN LANE 63 of every wave.
    // ONE (lgkm-only) barrier per call; barrier couples both samples' teams
    // (identical instruction structure => negligible lockstep cost).
    auto mlp_o63 = [&](float h1, float (*part)[64], float* o) {
        // self-broadcast h1 within wave (identical across the team's 4 waves)
        hc[wid][lane] = h1;
        const float* hq = &hc[wid][qk * 16];
        float4v q0 = *reinterpret_cast<const float4v*>(hq + 0);
        float4v q1 = *reinterpret_cast<const float4v*>(hq + 4);
        float4v q2 = *reinterpret_cast<const float4v*>(hq + 8);
        float4v q3 = *reinterpret_cast<const float4v*>(hq + 12);
        // L2 partial: 16-deep over this lane's K-subslice, output col2
        float2v a0 = float2v{0.0f, 0.0f}, a1 = float2v{0.0f, 0.0f};
        a0 = pk_fma(w2n[0], vlo(q0), a0); a1 = pk_fma(w2n[1], vhi(q0), a1);
        a0 = pk_fma(w2n[2], vlo(q1), a0); a1 = pk_fma(w2n[3], vhi(q1), a1);
        a0 = pk_fma(w2n[4], vlo(q2), a0); a1 = pk_fma(w2n[5], vhi(q2), a1);
        a0 = pk_fma(w2n[6], vlo(q3), a0); a1 = pk_fma(w2n[7], vhi(q3), a1);
        float2v sa = a0 + a1;
        float t2 = quad_sum(sa.x + sa.y);           // full 64-deep dot in quad
        float h2 = ftanh(t2 + b2s);
        // L3: h2 consumption is WAVE-UNIFORM (this team's 16 values resident
        // quad-redundant in lanes 4j) -> 16 readlane->SGPR + 16 v_fmac.
        float c0 = b3v, c1 = 0.0f, c2 = 0.0f, c3 = 0.0f;
#pragma unroll
        for (int j = 0; j < 16; j += 4) {
            float s0 = rl(h2, 4 * j);
            float s1 = rl(h2, 4 * (j + 1));
            float s2 = rl(h2, 4 * (j + 2));
            float s3 = rl(h2, 4 * (j + 3));
            c0 = fmaf(w3f[j + 0], s0, c0);
            c1 = fmaf(w3f[j + 1], s1, c1);
            c2 = fmaf(w3f[j + 2], s2, c2);
            c3 = fmaf(w3f[j + 3], s3, c3);
        }
        part[wq][lane] = (c0 + c1) + (c2 + c3);
        barrier_lgkm();                              // the ONE barrier (lgkm-only)
        float h3 = ftanh((part[0][lane] + part[1][lane]) + (part[2][lane] + part[3][lane]));
        // L4: 5 DPP trees, redundant in every wave (no LDS, no barrier)
#pragma unroll
        for (int k = 0; k < 5; ++k) o[k] = wave_sum63(w4r[k] * h3) + b4r[k];
    };

    // rhs: d0,d1 wave-uniform via readlane(63); o4 valid in lane 63 only.
    auto rhs = [&](float base, float y0v, float y1v, float ld, float snt,
                   float (*part)[64], float& d0, float& d1, float& o4) {
        // state-only nonlinearities first: overlap with the matvecs
        float step0 = fstep(y0v);
        float st1   = fstep(y1v);
        float h1 = ftanh(fmaf(w1r[0], y0v, fmaf(w1r[1], y1v, base)));
        float o[5];
        mlp_o63(h1, part, o);
        // epilogue computed with lane-63 values (garbage in other lanes, unused)
        float psnow = fmaxf(0.0f, fsinh(o[0]) * snt);
        float prain = fmaxf(0.0f, fsinh(o[1]));
        float melt  = fmaxf(0.0f, step0 * fsinh(o[2]));
        float eq    = st1 * fmaf(fexp(o[3]), ld, fexp(o[4]));
        float d0l = psnow - melt;
        float d1l = (prain + melt) - eq;
        d0 = rl(d0l, 63);
        d1 = rl(d1l, 63);
        o4 = o[4];
    };

    // wave-uniform state, replicated across the team (identical arithmetic)
    float y0v = g_snow[bs * T];
    float y1v = g_water[bs * T];

    const float* pr = s_pr[samp];
    const float* tm = s_tm[samp];
    const float* ld = s_ld[samp];
    float (*pA)[64] = partAB[samp][0];
    float (*pB)[64] = partAB[samp][1];

    for (int st = 0; st < T - 1; ++st) {
        float prc = pr[st], prn = pr[st + 1];
        float tmc = tm[st], tmn = tm[st + 1];
        float ldc = ld[st], ldn = ld[st + 1];

        float prH = 0.5f * (prc + prn);
        float tmH = 0.5f * (tmc + tmn);
        float ldH = 0.5f * (ldc + ldn);
        float snA = fstep(-tmc), snH = fstep(-tmH), snC = fstep(-tmn);
        float baseA = fmaf(w1r[2], prc, fmaf(w1r[3], tmc, b1v));
        float baseH = fmaf(w1r[2], prH, fmaf(w1r[3], tmH, b1v));
        float baseC = fmaf(w1r[2], prn, fmaf(w1r[3], tmn, b1v));

        float k1a, k1b, k2a, k2b, k3a, k3b, k4a, k4b, o4a, o4x;
        rhs(baseA, y0v, y1v, ldc, snA, pA, k1a, k1b, o4a);
        // q_out[:, st] == o[4] of the k1 MLP eval (integer-time interp == raw series)
        if (wq == 0 && lane == 63) out[bs * T + st] = o4a;
        rhs(baseH, fmaf(half, k1a, y0v), fmaf(half, k1b, y1v), ldH, snH, pB, k2a, k2b, o4x);
        rhs(baseH, fmaf(half, k2a, y0v), fmaf(half, k2b, y1v), ldH, snH, pA, k3a, k3b, o4x);
        rhs(baseC, fmaf(dtg,  k3a, y0v), fmaf(dtg,  k3b, y1v), ldn, snC, pB, k4a, k4b, o4x);

        y0v = fmaf(c6, (k1a + k4a) + 2.0f * (k2a + k3a), y0v);
        y1v = fmaf(c6, (k1b + k4b) + 2.0f * (k2b + k3b), y1v);
    }

    // last readout at t = T-1 with raw series values and final state
    {
        float base = fmaf(w1r[2], pr[T - 1], fmaf(w1r[3], tm[T - 1], b1v));
        float h1 = ftanh(fmaf(w1r[0], y0v, fmaf(w1r[1], y1v, base)));
        float o[5];
        mlp_o63(h1, pA, o);
        if (wq == 0 && lane == 63) out[bs * T + (T - 1)] = o[4];
    }
}

extern "C" void kernel_launch(void* const* d_in, const int* in_sizes, int n_in,
                              void* d_out, int out_size, void* d_ws, size_t ws_size,
                              hipStream_t stream) {
    const float* g_snow  = (const float*)d_in[0];
    const float* g_water = (const float*)d_in[1];
    const float* g_pr    = (const float*)d_in[2];
    const float* g_tm    = (const float*)d_in[3];
    const float* g_ld    = (const float*)d_in[4];
    const float* g_t     = (const float*)d_in[5];
    const float* W1 = (const float*)d_in[6];
    const float* b1 = (const float*)d_in[7];
    const float* W2 = (const float*)d_in[8];
    const float* b2 = (const float*)d_in[9];
    const float* W3 = (const float*)d_in[10];
    const float* b3 = (const float*)d_in[11];
    const float* W4 = (const float*)d_in[12];
    const float* b4 = (const float*)d_in[13];

    const int T = in_sizes[5];
    const int B = in_sizes[0] / T;
    const int nblk = (B + 1) / 2;

    exphydro_kernel<<<dim3(nblk), dim3(512), 0, stream>>>(
        g_snow, g_water, g_pr, g_tm, g_ld, g_t,
        W1, b1, W2, b2, W3, b3, W4, b4,
        (float*)d_out, T, B);
}

// Round 13
// 4907.701 us; speedup vs baseline: 1.4122x; 1.4122x over previous
//
#include <hip/hip_runtime.h>
#include <cmath>

#define LOG2E 1.44269504088896340736f
#define TMAX 2048

#if __has_builtin(__builtin_amdgcn_exp2f)
#define EXP2F(x) __builtin_amdgcn_exp2f(x)
#else
#define EXP2F(x) exp2f(x)
#endif
#if __has_builtin(__builtin_amdgcn_rcpf)
#define RCPF(x) __builtin_amdgcn_rcpf(x)
#else
#define RCPF(x) (1.0f / (x))
#endif

typedef float float2v __attribute__((ext_vector_type(2)));
typedef float float4v __attribute__((ext_vector_type(4)));

// tanh from a PRE-SCALED argument z = 2*log2e*x  (weights pre-scaled at load)
__device__ __forceinline__ float ftanh_z(float z) { return 1.0f - 2.0f * RCPF(1.0f + EXP2F(z)); }
// _step(x) = sigmoid(10x)
__device__ __forceinline__ float fstep(float x) { return RCPF(1.0f + EXP2F(x * (-10.0f * LOG2E))); }

__device__ __forceinline__ int fadd_i(int a, int b) {
    return __builtin_bit_cast(int, __builtin_bit_cast(float, a) + __builtin_bit_cast(float, b));
}

// full-wave (64 lane) sum via DPP tree; TOTAL VALID IN LANE 63 ONLY.
__device__ __forceinline__ float wave_sum63(float x) {
    int v = __builtin_bit_cast(int, x);
    v = fadd_i(v, __builtin_amdgcn_update_dpp(0, v, 0x111, 0xF, 0xF, true)); // row_shr:1
    v = fadd_i(v, __builtin_amdgcn_update_dpp(0, v, 0x112, 0xF, 0xF, true)); // row_shr:2
    v = fadd_i(v, __builtin_amdgcn_update_dpp(0, v, 0x114, 0xF, 0xF, true)); // row_shr:4
    v = fadd_i(v, __builtin_amdgcn_update_dpp(0, v, 0x118, 0xF, 0xF, true)); // row_shr:8
    v = fadd_i(v, __builtin_amdgcn_update_dpp(0, v, 0x142, 0xA, 0xF, true)); // row_bcast:15
    v = fadd_i(v, __builtin_amdgcn_update_dpp(0, v, 0x143, 0xC, 0xF, true)); // row_bcast:31
    return __builtin_bit_cast(float, v);
}

// quad (4-lane) all-sum via 2 DPP quad_perm adds (valid in all 4 lanes)
__device__ __forceinline__ float quad_sum(float x) {
    int v = __builtin_bit_cast(int, x);
    v = fadd_i(v, __builtin_amdgcn_update_dpp(0, v, 0xB1, 0xF, 0xF, true)); // quad_perm [1,0,3,2]
    v = fadd_i(v, __builtin_amdgcn_update_dpp(0, v, 0x4E, 0xF, 0xF, true)); // quad_perm [2,3,0,1]
    return __builtin_bit_cast(float, v);
}

// broadcast lane l's value to all lanes (lands in SGPR)
__device__ __forceinline__ float rl(float x, int l) {
    return __builtin_bit_cast(float, __builtin_amdgcn_readlane(__builtin_bit_cast(int, x), l));
}

// packed fp32 fma: d = a*b + c on both 32-bit halves (one VOP3P inst)
__device__ __forceinline__ float2v pk_fma(float2v a, float2v b, float2v c) {
    float2v d;
    asm("v_pk_fma_f32 %0, %1, %2, %3" : "=v"(d) : "v"(a), "v"(b), "v"(c));
    return d;
}

__device__ __forceinline__ float2v vlo(float4v v) { return __builtin_shufflevector(v, v, 0, 1); }
__device__ __forceinline__ float2v vhi(float4v v) { return __builtin_shufflevector(v, v, 2, 3); }

// lgkmcnt-only barrier: ds_writes must be LDS-visible, but do NOT drain vmcnt
// (the per-step `out` global store would otherwise stall every wave here).
__device__ __forceinline__ void barrier_lgkm() {
    asm volatile("s_waitcnt lgkmcnt(0)" ::: "memory");
    __builtin_amdgcn_s_barrier();
    asm volatile("" ::: "memory");
}

__global__ __launch_bounds__(256, 1)
void exphydro_kernel(const float* __restrict__ g_snow, const float* __restrict__ g_water,
                     const float* __restrict__ g_pr, const float* __restrict__ g_tm,
                     const float* __restrict__ g_ld, const float* __restrict__ g_t,
                     const float* __restrict__ W1, const float* __restrict__ b1,
                     const float* __restrict__ W2, const float* __restrict__ b2,
                     const float* __restrict__ W3, const float* __restrict__ b3,
                     const float* __restrict__ W4, const float* __restrict__ b4,
                     float* __restrict__ out, int T)
{
    const int tid  = threadIdx.x;
    const int lane = tid & 63;
    const int wid  = tid >> 6;     // wave id 0..3, one SIMD each
    const int b    = blockIdx.x;   // one sample per block
    const int qk   = lane & 3;     // L2: K-subslice (rows [qk*16, qk*16+16))
    const int qo   = lane >> 2;    // L2: output index within this wave's slice
    const int col2 = 16 * wid + qo; // L2 output column this lane computes

    const float S2 = 2.0f * LOG2E;  // tanh pre-scale folded into weights

    // forcing interleaved {pr, tm, ld, t} per timestep -- broadcast b128 reads
    __shared__ __align__(16) float4v s_f[TMAX];
    // per-wave private h1 copy (in-wave DS order => no barrier)
    __shared__ __align__(16) float hc[4][64];
    // L3 partial exchange, double-buffered across consecutive rhs calls
    __shared__ __align__(16) float partAB[2][4][64];

    for (int i = tid; i < T; i += 256) {
        s_f[i] = float4v{g_pr[b * T + i], g_tm[b * T + i], g_ld[b * T + i], g_t[i]};
    }

    // --- weights (W1/W2/W3 and their biases PRE-SCALED by 2*log2e) ---
    float w1s[4];
#pragma unroll
    for (int j = 0; j < 4; ++j) w1s[j] = W1[j * 64 + lane] * S2;
    float b1s = b1[lane] * S2;
    // layer 2, N-split: lane computes output col2 over K-rows [qk*16, qk*16+16)
    float2v w2n[8];
#pragma unroll
    for (int k = 0; k < 8; ++k) {
        int r = qk * 16 + 2 * k;
        w2n[k] = float2v{W2[r * 64 + col2] * S2, W2[(r + 1) * 64 + col2] * S2};
    }
    float b2s = b2[col2] * S2;
    // layer 3, K-split: wave owns rows [16*wid, 16*wid+16), lane = output col.
    float w3f[16];
#pragma unroll
    for (int k = 0; k < 16; ++k) w3f[k] = W3[(16 * wid + k) * 64 + lane] * S2;
    float b3v = (wid == 0) ? b3[lane] * S2 : 0.0f;
    // layer 4: full, redundant per wave; bias folded into epilogue exp2 consts
    float w4r[5];
#pragma unroll
    for (int k = 0; k < 5; ++k) w4r[k] = W4[lane * 5 + k];
    const float C0 = b4[0] * LOG2E, C1 = b4[1] * LOG2E, C2 = b4[2] * LOG2E,
                C3 = b4[3] * LOG2E, C4 = b4[4] * LOG2E;
    const float b44 = b4[4];

    __syncthreads();

    // MLP from per-lane h1 -> PRE-BIAS trees t[0..4], VALID IN LANE 63 of
    // every wave. ONE (lgkm-only) barrier per call.
    auto mlp_t63 = [&](float h1, float (*part)[64], float* t) {
        // self-broadcast h1 within wave (h1 is identical in all waves)
        hc[wid][lane] = h1;
        const float* hq = &hc[wid][qk * 16];
        float4v q0 = *reinterpret_cast<const float4v*>(hq + 0);
        float4v q1 = *reinterpret_cast<const float4v*>(hq + 4);
        float4v q2 = *reinterpret_cast<const float4v*>(hq + 8);
        float4v q3 = *reinterpret_cast<const float4v*>(hq + 12);
        // L2 partial: 16-deep over this lane's K-subslice, output col2 (scaled)
        float2v a0 = float2v{0.0f, 0.0f}, a1 = float2v{0.0f, 0.0f};
        a0 = pk_fma(w2n[0], vlo(q0), a0); a1 = pk_fma(w2n[1], vhi(q0), a1);
        a0 = pk_fma(w2n[2], vlo(q1), a0); a1 = pk_fma(w2n[3], vhi(q1), a1);
        a0 = pk_fma(w2n[4], vlo(q2), a0); a1 = pk_fma(w2n[5], vhi(q2), a1);
        a0 = pk_fma(w2n[6], vlo(q3), a0); a1 = pk_fma(w2n[7], vhi(q3), a1);
        float2v sa = a0 + a1;
        float z2 = quad_sum(sa.x + sa.y);           // scaled full 64-deep dot
        float h2 = ftanh_z(z2 + b2s);
        // L3: h2 consumption is WAVE-UNIFORM -> hoist ALL 16 readlanes first
        // (independent, pipelined), then 16 fmac on 4 chains.
        float hv[16];
#pragma unroll
        for (int j = 0; j < 16; ++j) hv[j] = rl(h2, 4 * j);
        float c0 = b3v, c1 = 0.0f, c2 = 0.0f, c3 = 0.0f;
#pragma unroll
        for (int j = 0; j < 16; j += 4) {
            c0 = fmaf(w3f[j + 0], hv[j + 0], c0);
            c1 = fmaf(w3f[j + 1], hv[j + 1], c1);
            c2 = fmaf(w3f[j + 2], hv[j + 2], c2);
            c3 = fmaf(w3f[j + 3], hv[j + 3], c3);
        }
        part[wid][lane] = (c0 + c1) + (c2 + c3);
        barrier_lgkm();                              // the ONE barrier (lgkm-only)
        float h3 = ftanh_z((part[0][lane] + part[1][lane]) + (part[2][lane] + part[3][lane]));
        // L4: 5 DPP trees (pre-bias), redundant in every wave
#pragma unroll
        for (int k = 0; k < 5; ++k) t[k] = wave_sum63(w4r[k] * h3);
    };

    // rhs: d0,d1 wave-uniform via readlane(63); o4 valid in lane 63 only.
    // sn05 = 0.5*fstep(-tm) precomputed per interp point (off-chain).
    auto rhs = [&](float base, float y0v, float y1v, float ld, float sn05,
                   float (*part)[64], float& d0, float& d1, float& o4) {
        // state-only nonlinearities first: overlap with the matvecs
        float step05 = 0.5f * fstep(y0v);
        float st1    = fstep(y1v);
        float h1 = ftanh_z(fmaf(w1s[0], y0v, fmaf(w1s[1], y1v, base)));
        float t[5];
        mlp_t63(h1, part, t);
        // epilogue (lane-63 values; garbage in other lanes, unused):
        // exp(o[k]) = exp2(t[k]*log2e + b4[k]*log2e), b4 folded into C[k]
        float e0 = EXP2F(fmaf(t[0], LOG2E, C0));
        float e1 = EXP2F(fmaf(t[1], LOG2E, C1));
        float e2 = EXP2F(fmaf(t[2], LOG2E, C2));
        float e3 = EXP2F(fmaf(t[3], LOG2E, C3));
        float e4 = EXP2F(fmaf(t[4], LOG2E, C4));
        float psnow = fmaxf(0.0f, (e0 - RCPF(e0)) * sn05);
        float prain = fmaxf(0.0f, 0.5f * (e1 - RCPF(e1)));
        float melt  = fmaxf(0.0f, (e2 - RCPF(e2)) * step05);
        float eq    = st1 * fmaf(e3, ld, e4);
        float d0l = psnow - melt;
        float d1l = (prain + melt) - eq;
        d0 = rl(d0l, 63);
        d1 = rl(d1l, 63);
        o4 = t[4] + b44;
    };

    // wave-uniform state, replicated per wave (identical arithmetic => identical)
    float y0v = g_snow[b * T];
    float y1v = g_water[b * T];

    for (int st = 0; st < T - 1; ++st) {
        float4v fc = s_f[st];
        float4v fn = s_f[st + 1];

        float dt = fn.w - fc.w, half = 0.5f * dt, c6 = dt * (1.0f / 6.0f);
        float prH = 0.5f * (fc.x + fn.x);
        float tmH = 0.5f * (fc.y + fn.y);
        float ldH = 0.5f * (fc.z + fn.z);
        float snA = 0.5f * fstep(-fc.y), snH = 0.5f * fstep(-tmH), snC = 0.5f * fstep(-fn.y);
        float baseA = fmaf(w1s[2], fc.x, fmaf(w1s[3], fc.y, b1s));
        float baseH = fmaf(w1s[2], prH,  fmaf(w1s[3], tmH,  b1s));
        float baseC = fmaf(w1s[2], fn.x, fmaf(w1s[3], fn.y, b1s));

        float k1a, k1b, k2a, k2b, k3a, k3b, k4a, k4b, o4a, o4x;
        rhs(baseA, y0v, y1v, fc.z, snA, partAB[0], k1a, k1b, o4a);
        // q_out[:, st] == o[4] of the k1 MLP eval (integer-time interp == raw series)
        if (tid == 63) out[b * T + st] = o4a;
        rhs(baseH, fmaf(half, k1a, y0v), fmaf(half, k1b, y1v), ldH, snH, partAB[1], k2a, k2b, o4x);
        rhs(baseH, fmaf(half, k2a, y0v), fmaf(half, k2b, y1v), ldH, snH, partAB[0], k3a, k3b, o4x);
        rhs(baseC, fmaf(dt, k3a, y0v),   fmaf(dt, k3b, y1v),   fn.z, snC, partAB[1], k4a, k4b, o4x);

        y0v = fmaf(c6, (k1a + k4a) + 2.0f * (k2a + k3a), y0v);
        y1v = fmaf(c6, (k1b + k4b) + 2.0f * (k2b + k3b), y1v);
    }

    // last readout at t = T-1 with raw series values and final state
    {
        float4v fL = s_f[T - 1];
        float base = fmaf(w1s[2], fL.x, fmaf(w1s[3], fL.y, b1s));
        float h1 = ftanh_z(fmaf(w1s[0], y0v, fmaf(w1s[1], y1v, base)));
        float t[5];
        mlp_t63(h1, partAB[0], t);
        if (tid == 63) out[b * T + (T - 1)] = t[4] + b44;
    }
}

extern "C" void kernel_launch(void* const* d_in, const int* in_sizes, int n_in,
                              void* d_out, int out_size, void* d_ws, size_t ws_size,
                              hipStream_t stream) {
    const float* g_snow  = (const float*)d_in[0];
    const float* g_water = (const float*)d_in[1];
    const float* g_pr    = (const float*)d_in[2];
    const float* g_tm    = (const float*)d_in[3];
    const float* g_ld    = (const float*)d_in[4];
    const float* g_t     = (const float*)d_in[5];
    const float* W1 = (const float*)d_in[6];
    const float* b1 = (const float*)d_in[7];
    const float* W2 = (const float*)d_in[8];
    const float* b2 = (const float*)d_in[9];
    const float* W3 = (const float*)d_in[10];
    const float* b3 = (const float*)d_in[11];
    const float* W4 = (const float*)d_in[12];
    const float* b4 = (const float*)d_in[13];

    const int T = in_sizes[5];
    const int B = in_sizes[0] / T;

    exphydro_kernel<<<dim3(B), dim3(256), 0, stream>>>(
        g_snow, g_water, g_pr, g_tm, g_ld, g_t,
        W1, b1, W2, b2, W3, b3, W4, b4,
        (float*)d_out, T);
}

// Round 14
// 4807.468 us; speedup vs baseline: 1.4417x; 1.0208x over previous
//
#include <hip/hip_runtime.h>
#include <cmath>

#define LOG2E 1.44269504088896340736f
#define TMAX 2048

#if __has_builtin(__builtin_amdgcn_exp2f)
#define EXP2F(x) __builtin_amdgcn_exp2f(x)
#else
#define EXP2F(x) exp2f(x)
#endif
#if __has_builtin(__builtin_amdgcn_rcpf)
#define RCPF(x) __builtin_amdgcn_rcpf(x)
#else
#define RCPF(x) (1.0f / (x))
#endif

typedef float float2v __attribute__((ext_vector_type(2)));
typedef float float4v __attribute__((ext_vector_type(4)));

__device__ __forceinline__ float fexp(float x)  { return EXP2F(x * LOG2E); }
// tanh(x) = 1 - 2/(1 + e^{2x})
__device__ __forceinline__ float ftanh(float x) { return 1.0f - 2.0f * RCPF(1.0f + EXP2F(x * (2.0f * LOG2E))); }
// _step(x) = (tanh(5x)+1)/2 = sigmoid(10x)
__device__ __forceinline__ float fstep(float x) { return RCPF(1.0f + EXP2F(x * (-10.0f * LOG2E))); }
__device__ __forceinline__ float fsinh(float x) { float e = fexp(x); return 0.5f * (e - RCPF(e)); }

__device__ __forceinline__ int fadd_i(int a, int b) {
    return __builtin_bit_cast(int, __builtin_bit_cast(float, a) + __builtin_bit_cast(float, b));
}

// full-wave (64 lane) sum via DPP tree; TOTAL VALID IN LANE 63 ONLY.
__device__ __forceinline__ float wave_sum63(float x) {
    int v = __builtin_bit_cast(int, x);
    v = fadd_i(v, __builtin_amdgcn_update_dpp(0, v, 0x111, 0xF, 0xF, true)); // row_shr:1
    v = fadd_i(v, __builtin_amdgcn_update_dpp(0, v, 0x112, 0xF, 0xF, true)); // row_shr:2
    v = fadd_i(v, __builtin_amdgcn_update_dpp(0, v, 0x114, 0xF, 0xF, true)); // row_shr:4
    v = fadd_i(v, __builtin_amdgcn_update_dpp(0, v, 0x118, 0xF, 0xF, true)); // row_shr:8
    v = fadd_i(v, __builtin_amdgcn_update_dpp(0, v, 0x142, 0xA, 0xF, true)); // row_bcast:15
    v = fadd_i(v, __builtin_amdgcn_update_dpp(0, v, 0x143, 0xC, 0xF, true)); // row_bcast:31
    return __builtin_bit_cast(float, v);
}

// quad (4-lane) all-sum via 2 DPP quad_perm adds (valid in all 4 lanes)
__device__ __forceinline__ float quad_sum(float x) {
    int v = __builtin_bit_cast(int, x);
    v = fadd_i(v, __builtin_amdgcn_update_dpp(0, v, 0xB1, 0xF, 0xF, true)); // quad_perm [1,0,3,2]
    v = fadd_i(v, __builtin_amdgcn_update_dpp(0, v, 0x4E, 0xF, 0xF, true)); // quad_perm [2,3,0,1]
    return __builtin_bit_cast(float, v);
}

// broadcast lane l's value to all lanes (lands in SGPR)
__device__ __forceinline__ float rl(float x, int l) {
    return __builtin_bit_cast(float, __builtin_amdgcn_readlane(__builtin_bit_cast(int, x), l));
}

// packed fp32 fma: d = a*b + c on both 32-bit halves (one VOP3P inst)
__device__ __forceinline__ float2v pk_fma(float2v a, float2v b, float2v c) {
    float2v d;
    asm("v_pk_fma_f32 %0, %1, %2, %3" : "=v"(d) : "v"(a), "v"(b), "v"(c));
    return d;
}

__device__ __forceinline__ float2v vlo(float4v v) { return __builtin_shufflevector(v, v, 0, 1); }
__device__ __forceinline__ float2v vhi(float4v v) { return __builtin_shufflevector(v, v, 2, 3); }

// lgkmcnt-only barrier: ds_writes must be LDS-visible, but do NOT drain vmcnt
// (the per-step `out` global store would otherwise stall every wave here).
__device__ __forceinline__ void barrier_lgkm() {
    asm volatile("s_waitcnt lgkmcnt(0)" ::: "memory");
    __builtin_amdgcn_s_barrier();
    asm volatile("" ::: "memory");
}

__global__ __launch_bounds__(256, 1)
void exphydro_kernel(const float* __restrict__ g_snow, const float* __restrict__ g_water,
                     const float* __restrict__ g_pr, const float* __restrict__ g_tm,
                     const float* __restrict__ g_ld, const float* __restrict__ g_t,
                     const float* __restrict__ W1, const float* __restrict__ b1,
                     const float* __restrict__ W2, const float* __restrict__ b2,
                     const float* __restrict__ W3, const float* __restrict__ b3,
                     const float* __restrict__ W4, const float* __restrict__ b4,
                     float* __restrict__ out, int T)
{
    const int tid  = threadIdx.x;
    const int lane = tid & 63;
    const int wid  = tid >> 6;     // wave id 0..3, one SIMD each
    const int b    = blockIdx.x;   // one sample per block
    const int qk   = lane & 3;     // L2: K-subslice (rows [qk*16, qk*16+16))
    const int qo   = lane >> 2;    // L2: output index within this wave's slice
    const int col2 = 16 * wid + qo; // L2 output column this lane computes

    // forcing interleaved {pr, tm, ld, t} per timestep -- broadcast b128 reads
    __shared__ __align__(16) float4v s_f[TMAX];
    // per-wave private h1 copy (in-wave DS order => no barrier)
    __shared__ __align__(16) float hc[4][64];
    // L3 partial exchange, double-buffered across consecutive rhs calls
    __shared__ __align__(16) float partAB[2][4][64];

    for (int i = tid; i < T; i += 256) {
        s_f[i] = float4v{g_pr[b * T + i], g_tm[b * T + i], g_ld[b * T + i], g_t[i]};
    }

    // --- weights ---
    // layer 1: all waves identical (per-lane column)
    float w1r[4];
#pragma unroll
    for (int j = 0; j < 4; ++j) w1r[j] = W1[j * 64 + lane];
    float b1v = b1[lane];
    // layer 2, N-split: lane computes output col2 over K-rows [qk*16, qk*16+16)
    float2v w2n[8];
#pragma unroll
    for (int k = 0; k < 8; ++k) {
        int r = qk * 16 + 2 * k;
        w2n[k] = float2v{W2[r * 64 + col2], W2[(r + 1) * 64 + col2]};
    }
    float b2s = b2[col2];
    // layer 3, K-split: wave owns rows [16*wid, 16*wid+16), lane = output col.
    // Scalar layout (consumed with SGPR-broadcast h2 via v_fmac).
    float w3f[16];
#pragma unroll
    for (int k = 0; k < 16; ++k) w3f[k] = W3[(16 * wid + k) * 64 + lane];
    float b3v = (wid == 0) ? b3[lane] : 0.0f;
    // layer 4: full, redundant per wave
    float w4r[5], b4r[5];
#pragma unroll
    for (int k = 0; k < 5; ++k) { w4r[k] = W4[lane * 5 + k]; b4r[k] = b4[k]; }

    __syncthreads();

    // full MLP from per-lane h1; o[0..4] VALID IN LANE 63 of every wave.
    // ONE (lgkm-only) barrier per call.
    auto mlp_o63 = [&](float h1, float (*part)[64], float* o) {
        // self-broadcast h1 within wave (h1 is identical in all waves)
        hc[wid][lane] = h1;
        const float* hq = &hc[wid][qk * 16];
        float4v q0 = *reinterpret_cast<const float4v*>(hq + 0);
        float4v q1 = *reinterpret_cast<const float4v*>(hq + 4);
        float4v q2 = *reinterpret_cast<const float4v*>(hq + 8);
        float4v q3 = *reinterpret_cast<const float4v*>(hq + 12);
        // L2 partial: 16-deep over this lane's K-subslice, output col2
        float2v a0 = float2v{0.0f, 0.0f}, a1 = float2v{0.0f, 0.0f};
        a0 = pk_fma(w2n[0], vlo(q0), a0); a1 = pk_fma(w2n[1], vhi(q0), a1);
        a0 = pk_fma(w2n[2], vlo(q1), a0); a1 = pk_fma(w2n[3], vhi(q1), a1);
        a0 = pk_fma(w2n[4], vlo(q2), a0); a1 = pk_fma(w2n[5], vhi(q2), a1);
        a0 = pk_fma(w2n[6], vlo(q3), a0); a1 = pk_fma(w2n[7], vhi(q3), a1);
        float2v sa = a0 + a1;
        float t2 = quad_sum(sa.x + sa.y);           // full 64-deep dot in quad
        float h2 = ftanh(t2 + b2s);
        // L3: h2 consumption is WAVE-UNIFORM (this wave's 16 values, resident
        // quad-redundant in lanes 4j) -> 16 readlane->SGPR + 16 v_fmac.
        float c0 = b3v, c1 = 0.0f, c2 = 0.0f, c3 = 0.0f;
#pragma unroll
        for (int j = 0; j < 16; j += 4) {
            float s0 = rl(h2, 4 * j);
            float s1 = rl(h2, 4 * (j + 1));
            float s2 = rl(h2, 4 * (j + 2));
            float s3 = rl(h2, 4 * (j + 3));
            c0 = fmaf(w3f[j + 0], s0, c0);
            c1 = fmaf(w3f[j + 1], s1, c1);
            c2 = fmaf(w3f[j + 2], s2, c2);
            c3 = fmaf(w3f[j + 3], s3, c3);
        }
        part[wid][lane] = (c0 + c1) + (c2 + c3);
        barrier_lgkm();                              // the ONE barrier (lgkm-only)
        float h3 = ftanh((part[0][lane] + part[1][lane]) + (part[2][lane] + part[3][lane]));
        // L4: 5 DPP trees, redundant in every wave (no LDS, no barrier)
#pragma unroll
        for (int k = 0; k < 5; ++k) o[k] = wave_sum63(w4r[k] * h3) + b4r[k];
    };

    // rhs: d0,d1 wave-uniform via readlane(63); o4 valid in lane 63 only.
    auto rhs = [&](float base, float y0v, float y1v, float ld, float snt,
                   float (*part)[64], float& d0, float& d1, float& o4) {
        // state-only nonlinearities first: overlap with the matvecs
        float step0 = fstep(y0v);
        float st1   = fstep(y1v);
        float h1 = ftanh(fmaf(w1r[0], y0v, fmaf(w1r[1], y1v, base)));
        float o[5];
        mlp_o63(h1, part, o);
        // epilogue computed with lane-63 values (garbage in other lanes, unused)
        float psnow = fmaxf(0.0f, fsinh(o[0]) * snt);
        float prain = fmaxf(0.0f, fsinh(o[1]));
        float melt  = fmaxf(0.0f, step0 * fsinh(o[2]));
        float eq    = st1 * fmaf(fexp(o[3]), ld, fexp(o[4]));
        float d0l = psnow - melt;
        float d1l = (prain + melt) - eq;
        d0 = rl(d0l, 63);
        d1 = rl(d1l, 63);
        o4 = o[4];
    };

    // wave-uniform state, replicated per wave (identical arithmetic => identical)
    float y0v = g_snow[b * T];
    float y1v = g_water[b * T];

    for (int st = 0; st < T - 1; ++st) {
        float4v fc = s_f[st];
        float4v fn = s_f[st + 1];

        float dt = fn.w - fc.w, half = 0.5f * dt, c6 = dt * (1.0f / 6.0f);
        float prH = 0.5f * (fc.x + fn.x);
        float tmH = 0.5f * (fc.y + fn.y);
        float ldH = 0.5f * (fc.z + fn.z);
        float snA = fstep(-fc.y), snH = fstep(-tmH), snC = fstep(-fn.y);
        float baseA = fmaf(w1r[2], fc.x, fmaf(w1r[3], fc.y, b1v));
        float baseH = fmaf(w1r[2], prH,  fmaf(w1r[3], tmH,  b1v));
        float baseC = fmaf(w1r[2], fn.x, fmaf(w1r[3], fn.y, b1v));

        float k1a, k1b, k2a, k2b, k3a, k3b, k4a, k4b, o4a, o4x;
        rhs(baseA, y0v, y1v, fc.z, snA, partAB[0], k1a, k1b, o4a);
        // q_out[:, st] == o[4] of the k1 MLP eval (integer-time interp == raw series)
        if (tid == 63) out[b * T + st] = o4a;
        rhs(baseH, fmaf(half, k1a, y0v), fmaf(half, k1b, y1v), ldH, snH, partAB[1], k2a, k2b, o4x);
        rhs(baseH, fmaf(half, k2a, y0v), fmaf(half, k2b, y1v), ldH, snH, partAB[0], k3a, k3b, o4x);
        rhs(baseC, fmaf(dt, k3a, y0v),   fmaf(dt, k3b, y1v),   fn.z, snC, partAB[1], k4a, k4b, o4x);

        y0v = fmaf(c6, (k1a + k4a) + 2.0f * (k2a + k3a), y0v);
        y1v = fmaf(c6, (k1b + k4b) + 2.0f * (k2b + k3b), y1v);
    }

    // last readout at t = T-1 with raw series values and final state
    {
        float4v fL = s_f[T - 1];
        float base = fmaf(w1r[2], fL.x, fmaf(w1r[3], fL.y, b1v));
        float h1 = ftanh(fmaf(w1r[0], y0v, fmaf(w1r[1], y1v, base)));
        float o[5];
        mlp_o63(h1, partAB[0], o);
        if (tid == 63) out[b * T + (T - 1)] = o[4];
    }
}

extern "C" void kernel_launch(void* const* d_in, const int* in_sizes, int n_in,
                              void* d_out, int out_size, void* d_ws, size_t ws_size,
                              hipStream_t stream) {
    const float* g_snow  = (const float*)d_in[0];
    const float* g_water = (const float*)d_in[1];
    const float* g_pr    = (const float*)d_in[2];
    const float* g_tm    = (const float*)d_in[3];
    const float* g_ld    = (const float*)d_in[4];
    const float* g_t     = (const float*)d_in[5];
    const float* W1 = (const float*)d_in[6];
    const float* b1 = (const float*)d_in[7];
    const float* W2 = (const float*)d_in[8];
    const float* b2 = (const float*)d_in[9];
    const float* W3 = (const float*)d_in[10];
    const float* b3 = (const float*)d_in[11];
    const float* W4 = (const float*)d_in[12];
    const float* b4 = (const float*)d_in[13];

    const int T = in_sizes[5];
    const int B = in_sizes[0] / T;

    exphydro_kernel<<<dim3(B), dim3(256), 0, stream>>>(
        g_snow, g_water, g_pr, g_tm, g_ld, g_t,
        W1, b1, W2, b2, W3, b3, W4, b4,
        (float*)d_out, T);
}